// Round 11
// baseline (731.778 us; speedup 1.0000x reference)
//
#include <hip/hip_runtime.h>

#define NN     4096
#define NFEAT  512
#define NHID   64
#define NHEADS 8
#define NS     64
#define NEDGE  131072
#define NHH    512
#define MASKW  (NN/32)   // 128 words per row
#define JS     4         // j-split factor for attention

typedef _Float16 f16;
typedef _Float16 f16x4 __attribute__((ext_vector_type(4)));
typedef _Float16 f16x8 __attribute__((ext_vector_type(8)));
typedef float    f32x4 __attribute__((ext_vector_type(4)));

// ---------------- prep kernels ----------------

// pack adj (int32 0/1) into bitmask: bit b of word w = adj[w*32+b] > 0
__global__ __launch_bounds__(256) void k_pack_mask(const int* __restrict__ adj,
                                                   unsigned* __restrict__ mb) {
  int w = blockIdx.x * 256 + threadIdx.x;
  const int4* p = (const int4*)(adj + (size_t)w * 32);
  unsigned m = 0;
#pragma unroll
  for (int c = 0; c < 8; c++) {
    int4 v = p[c];
    m |= (v.x > 0 ? 1u : 0u) << (4*c)     | (v.y > 0 ? 1u : 0u) << (4*c + 1)
       | (v.z > 0 ? 1u : 0u) << (4*c + 2) | (v.w > 0 ? 1u : 0u) << (4*c + 3);
  }
  mb[w] = m;
}

__global__ __launch_bounds__(256) void k_cast(const float* __restrict__ in,
                                              f16* __restrict__ out, int n) {
  int i = blockIdx.x * 256 + threadIdx.x;
  if (i < n) out[i] = (f16)in[i];
}

// WcatT[n][k] = W_heads[n>>6][k][n&63]  (n = head*64+f), out [512][512] f16
__global__ __launch_bounds__(256) void k_wcatT(const float* __restrict__ W,
                                               f16* __restrict__ out) {
  int idx = blockIdx.x * 256 + threadIdx.x;
  int n = idx >> 9, k = idx & 511;
  out[idx] = (f16)W[(n >> 6) * (NFEAT * NHID) + k * NHID + (n & 63)];
}

// WoutT[n][k] = W_out[k][n]
__global__ __launch_bounds__(256) void k_transT(const float* __restrict__ W,
                                                f16* __restrict__ out) {
  int idx = blockIdx.x * 256 + threadIdx.x;
  int n = idx >> 9, k = idx & 511;
  out[idx] = (f16)W[k * NHH + n];
}

// hcat[i][512+c] = s[i][c]   (hcat leading dim 576)
__global__ __launch_bounds__(256) void k_s_hcat(const float* __restrict__ s,
                                                f16* __restrict__ hcat) {
  int idx = blockIdx.x * 256 + threadIdx.x;
  int i = idx >> 6, c = idx & 63;
  hcat[(size_t)i * 576 + 512 + c] = (f16)s[idx];
}

// ---------------- GEMM: C = A[M][lda] @ BT[n][k]^T ----------------
// MODE 0: store C^T as f16 into outT[n][ldo]   (ldo = M total)
// MODE 1: store C as f32 into out[m][ldo] (+ bias[n] if bias)
// MODE 2: store C as f16 into out[m][ldo] (+ bias[n] if bias)
// Contiguous-8 K-permutation; software-pipelined K loop (prefetch k0+32
// while computing k0) for memory-level parallelism.
template<int MODE>
__global__ __launch_bounds__(256) void k_gemm(const f16* __restrict__ A, int lda,
                                              const f16* __restrict__ BT, int ldbt,
                                              void* __restrict__ outp, int ldo,
                                              const float* __restrict__ bias, int K) {
  int w = threadIdx.x >> 6, l = threadIdx.x & 63;
  int g = l >> 4, ln = l & 15;
  int row  = blockIdx.x * 64 + w * 16 + ln;
  int colb = blockIdx.y * 64;
  const f16* ap = A + (size_t)row * lda + 8 * g;
  const f16* bp = BT + (size_t)(colb + ln) * ldbt + 8 * g;
  f32x4 acc[4];
#pragma unroll
  for (int nf = 0; nf < 4; nf++) acc[nf] = (f32x4){0.f, 0.f, 0.f, 0.f};
  f16x8 af = *(const f16x8*)(ap);
  f16x8 b0 = *(const f16x8*)(bp);
  f16x8 b1 = *(const f16x8*)(bp + (size_t)16 * ldbt);
  f16x8 b2 = *(const f16x8*)(bp + (size_t)32 * ldbt);
  f16x8 b3 = *(const f16x8*)(bp + (size_t)48 * ldbt);
  for (int k0 = 0; k0 < K; k0 += 32) {
    f16x8 ac = af, c0 = b0, c1 = b1, c2 = b2, c3 = b3;
    if (k0 + 32 < K) {
      af = *(const f16x8*)(ap + k0 + 32);
      b0 = *(const f16x8*)(bp + k0 + 32);
      b1 = *(const f16x8*)(bp + (size_t)16 * ldbt + k0 + 32);
      b2 = *(const f16x8*)(bp + (size_t)32 * ldbt + k0 + 32);
      b3 = *(const f16x8*)(bp + (size_t)48 * ldbt + k0 + 32);
    }
    acc[0] = __builtin_amdgcn_mfma_f32_16x16x32_f16(ac, c0, acc[0], 0, 0, 0);
    acc[1] = __builtin_amdgcn_mfma_f32_16x16x32_f16(ac, c1, acc[1], 0, 0, 0);
    acc[2] = __builtin_amdgcn_mfma_f32_16x16x32_f16(ac, c2, acc[2], 0, 0, 0);
    acc[3] = __builtin_amdgcn_mfma_f32_16x16x32_f16(ac, c3, acc[3], 0, 0, 0);
  }
  int m0 = blockIdx.x * 64 + w * 16 + 4 * g;   // C/D: col=lane&15, row=4*(l>>4)+r (m89)
#pragma unroll
  for (int nf = 0; nf < 4; nf++) {
    int n = colb + nf * 16 + ln;
    if (MODE == 0) {
      f16* oT = (f16*)outp;
      f16x4 v = {(f16)acc[nf][0], (f16)acc[nf][1], (f16)acc[nf][2], (f16)acc[nf][3]};
      *(f16x4*)(oT + (size_t)n * ldo + m0) = v;
    } else if (MODE == 1) {
      float* o = (float*)outp;
      float b = bias ? bias[n] : 0.f;
#pragma unroll
      for (int r = 0; r < 4; r++) o[(size_t)(m0 + r) * ldo + n] = acc[nf][r] + b;
    } else {
      f16* o = (f16*)outp;
      float b = bias ? bias[n] : 0.f;
#pragma unroll
      for (int r = 0; r < 4; r++) o[(size_t)(m0 + r) * ldo + n] = (f16)(acc[nf][r] + b);
    }
  }
}

// src[h][i] = sum_f WhT[h*fo+f][i]*a[h][f];  dst uses a[h][fo+f]
__global__ __launch_bounds__(256) void k_srcdst(const f16* __restrict__ WhT,
                                                const float* __restrict__ a,
                                                float* __restrict__ sv,
                                                float* __restrict__ dv, int fo) {
  int h = blockIdx.y;
  int i = blockIdx.x * 256 + threadIdx.x;
  const f16* wp = WhT + (size_t)h * fo * NN + i;
  const float* ap = a + h * 2 * fo;
  float sacc = 0.f, dacc = 0.f;
  for (int f = 0; f < fo; f++) {
    float v = (float)wp[(size_t)f * NN];
    sacc = fmaf(v, ap[f], sacc);
    dacc = fmaf(v, ap[fo + f], dacc);
  }
  sv[h * NN + i] = sacc;
  dv[h * NN + i] = dacc;
}

// ---------------- fused masked GAT attention (flash-style, j-split) ----------------
// grid (rowblocks=64, colblocks=8, JS). Block: 64 rows x 64 cols, j-range NN/JS.
// exp(e) needs no max-sub (|e|<~6) -> partial PV/rsum are linearly combinable.
// Hand software-pipelined: prefetch t+1's B-frags/dv/mask before t's exp+MFMA.
// launch_bounds(256,6): VGPR cap 85, 6 blocks/CU (75% occ) — r10 showed (,8)
// forced VGPR=32 and killed per-wave MLP (160us, VALU 25%).
__global__ __launch_bounds__(256, 6) void k_attn(const f16* __restrict__ WhT,
                                              const float* __restrict__ sv,
                                              const float* __restrict__ dv, int sstride,
                                              const unsigned* __restrict__ mb,
                                              float* __restrict__ pp,
                                              float* __restrict__ prs) {
  int w = threadIdx.x >> 6, l = threadIdx.x & 63;
  int g = l >> 4, ln = l & 15;
  int i = blockIdx.x * 64 + w * 16 + ln;        // this lane's A-frag row
  int colbase = blockIdx.y * 64;
  int jz = blockIdx.z;
  const int jbase = jz * (NN / JS);
  const int NT = (NN / JS) / 32;
  float si = sv[blockIdx.y * sstride + i];
  const float* dpj = dv + blockIdx.y * sstride + jbase + 8 * g;
  const unsigned* mrow = mb + (size_t)i * MASKW + (jbase >> 5);
  const f16* bp0 = WhT + (size_t)(colbase + ln) * NN + jbase + 8 * g;
  f32x4 acc[4];
#pragma unroll
  for (int nf = 0; nf < 4; nf++) acc[nf] = (f32x4){0.f, 0.f, 0.f, 0.f};
  float rsum = 0.f;
  // prologue loads (t = 0)
  unsigned m32 = mrow[0];
  f32x4 dlo = *(const f32x4*)(dpj);
  f32x4 dhi = *(const f32x4*)(dpj + 4);
  f16x8 b0 = *(const f16x8*)(bp0);
  f16x8 b1 = *(const f16x8*)(bp0 + (size_t)16 * NN);
  f16x8 b2 = *(const f16x8*)(bp0 + (size_t)32 * NN);
  f16x8 b3 = *(const f16x8*)(bp0 + (size_t)48 * NN);
  for (int t = 0; t < NT; ++t) {
    unsigned mc = m32;
    f32x4 dl = dlo, dh = dhi;
    f16x8 c0 = b0, c1 = b1, c2 = b2, c3 = b3;
    if (t + 1 < NT) {                            // prefetch t+1
      m32 = mrow[t + 1];
      dlo = *(const f32x4*)(dpj + (t + 1) * 32);
      dhi = *(const f32x4*)(dpj + (t + 1) * 32 + 4);
      b0 = *(const f16x8*)(bp0 + (t + 1) * 32);
      b1 = *(const f16x8*)(bp0 + (size_t)16 * NN + (t + 1) * 32);
      b2 = *(const f16x8*)(bp0 + (size_t)32 * NN + (t + 1) * 32);
      b3 = *(const f16x8*)(bp0 + (size_t)48 * NN + (t + 1) * 32);
    }
    f16x8 af;
#pragma unroll
    for (int d = 0; d < 4; d++) {
      float e = si + dl[d];
      e = fmaxf(e, 0.2f * e);                    // LeakyReLU(0.2)
      float we = __expf(e);
      we = ((mc >> (8 * g + d)) & 1u) ? we : 0.f;
      rsum += we;
      af[d] = (f16)we;
      float e2 = si + dh[d];
      e2 = fmaxf(e2, 0.2f * e2);
      float we2 = __expf(e2);
      we2 = ((mc >> (8 * g + 4 + d)) & 1u) ? we2 : 0.f;
      rsum += we2;
      af[4 + d] = (f16)we2;
    }
    acc[0] = __builtin_amdgcn_mfma_f32_16x16x32_f16(af, c0, acc[0], 0, 0, 0);
    acc[1] = __builtin_amdgcn_mfma_f32_16x16x32_f16(af, c1, acc[1], 0, 0, 0);
    acc[2] = __builtin_amdgcn_mfma_f32_16x16x32_f16(af, c2, acc[2], 0, 0, 0);
    acc[3] = __builtin_amdgcn_mfma_f32_16x16x32_f16(af, c3, acc[3], 0, 0, 0);
  }
  // full row sums over this j-range: 4 lanegroups hold disjoint partials of row (l&15)
  rsum += __shfl_xor(rsum, 16, 64);
  rsum += __shfl_xor(rsum, 32, 64);
  if (l < 16)
    prs[(size_t)jz * 8 * NN + blockIdx.y * NN + blockIdx.x * 64 + w * 16 + l] = rsum;
  float* o = pp + (size_t)jz * NN * NHH;
  int m0 = blockIdx.x * 64 + w * 16 + 4 * g;
#pragma unroll
  for (int nf = 0; nf < 4; nf++)
#pragma unroll
    for (int r = 0; r < 4; r++)
      o[(size_t)(m0 + r) * NHH + colbase + nf * 16 + ln] = acc[nf][r];
}

// combine j-split partials: out[i][c] = act( sum_jz pp / sum_jz prs )
template<bool ELU>
__global__ __launch_bounds__(256) void k_combine(const float* __restrict__ pp,
                                                 const float* __restrict__ prs,
                                                 f16* __restrict__ outp, int ldo) {
  int idx = blockIdx.x * 256 + threadIdx.x;       // over NN*NHH
  int i = idx >> 9, c = idx & 511;
  float s = 0.f, rs = 0.f;
#pragma unroll
  for (int jz = 0; jz < JS; jz++) {
    s  += pp[(size_t)jz * NN * NHH + idx];
    rs += prs[(size_t)jz * 8 * NN + (size_t)(c >> 6) * NN + i];
  }
  float v = s / rs;
  if (ELU) v = v > 0.f ? v : (__expf(v) - 1.f);
  outp[(size_t)i * ldo + c] = (f16)v;
}

// ---------------- edge MLP: out[e] = dot(relu(P[src]+Q[dst]), w2) + b2 ----------------
// P, Q in f16 (halves the random-row gather bytes; 8 MB -> L2/L3 resident)
__global__ __launch_bounds__(256) void k_edge(const f16* __restrict__ P,
                                              const f16* __restrict__ Q,
                                              const int* __restrict__ ids,
                                              const float* __restrict__ w2,
                                              const float* __restrict__ b2,
                                              float* __restrict__ out) {
  int t = blockIdx.x * 256 + threadIdx.x;
  int e = t >> 6, l = t & 63;                   // one wave per edge
  int sn = ids[2 * e], dn = ids[2 * e + 1];
  f16x8 pv = *(const f16x8*)(P + (size_t)sn * NHH + l * 8);
  f16x8 qv = *(const f16x8*)(Q + (size_t)dn * NHH + l * 8);
  const float* wv = w2 + l * 8;
  f32x4 w0 = *(const f32x4*)(wv);
  f32x4 w1 = *(const f32x4*)(wv + 4);
  float acc = 0.f;
#pragma unroll
  for (int u = 0; u < 4; u++) {
    float v = (float)pv[u] + (float)qv[u];
    acc = fmaf(fmaxf(v, 0.f), w0[u], acc);
    float v2 = (float)pv[4 + u] + (float)qv[4 + u];
    acc = fmaf(fmaxf(v2, 0.f), w1[u], acc);
  }
#pragma unroll
  for (int m = 1; m < 64; m <<= 1) acc += __shfl_xor(acc, m, 64);
  if (l == 0) out[e] = acc + b2[0];
}

// ---------------- launch ----------------
extern "C" void kernel_launch(void* const* d_in, const int* in_sizes, int n_in,
                              void* d_out, int out_size, void* d_ws, size_t ws_size,
                              hipStream_t stream) {
  const float* s   = (const float*)d_in[0];
  const float* x   = (const float*)d_in[1];
  const int*   adj = (const int*)d_in[2];
  const int*   ids = (const int*)d_in[3];
  const float* Whd = (const float*)d_in[4];
  const float* ah  = (const float*)d_in[5];
  const float* Wo  = (const float*)d_in[6];
  const float* ao  = (const float*)d_in[7];
  const float* W1  = (const float*)d_in[8];
  const float* b1  = (const float*)d_in[9];
  const float* W2  = (const float*)d_in[10];
  const float* b2  = (const float*)d_in[11];
  float* out = (float*)d_out;

  char* ws = (char*)d_ws;
  size_t off = 0;
  auto alloc = [&](size_t b) { char* p = ws + off; off += (b + 255) & ~(size_t)255; return p; };
  unsigned* mb  = (unsigned*)alloc((size_t)NN * MASKW * 4);   // 2 MB
  f16* xh       = (f16*)alloc((size_t)NN * NFEAT * 2);        // 4 MB
  f16* WcatT    = (f16*)alloc((size_t)NHH * NFEAT * 2);
  f16* WoutT    = (f16*)alloc((size_t)NHH * NHH * 2);
  f16* W1h      = (f16*)alloc((size_t)NHH * 1152 * 2);
  f16* WhT1     = (f16*)alloc((size_t)NHH * NN * 2);          // 4 MB
  f16* h1       = (f16*)alloc((size_t)NN * NHH * 2);          // 4 MB
  f16* WhT2     = (f16*)alloc((size_t)NHH * NN * 2);          // 4 MB
  f16* hcat     = (f16*)alloc((size_t)NN * 576 * 2);          // 4.5 MB
  float* sv1    = (float*)alloc((size_t)NHEADS * NN * 4);
  float* dv1    = (float*)alloc((size_t)NHEADS * NN * 4);
  float* sv2    = (float*)alloc((size_t)NN * 4);
  float* dv2    = (float*)alloc((size_t)NN * 4);
  // union region: attn partials (32.5 MB) then, after combine, Pb/Qb (f16, 4 MB each)
  char* region  = alloc((size_t)JS * NN * NHH * 4 + (size_t)JS * 8 * NN * 4);
  float* pp     = (float*)region;
  float* prs    = (float*)(region + (size_t)JS * NN * NHH * 4);
  f16* Pb       = (f16*)region;
  f16* Qb       = (f16*)(region + (size_t)NN * NHH * 2);

  k_pack_mask<<<NN * MASKW / 256, 256, 0, stream>>>(adj, mb);
  k_cast<<<NN * NFEAT / 256, 256, 0, stream>>>(x, xh, NN * NFEAT);
  k_wcatT<<<NHH * NFEAT / 256, 256, 0, stream>>>(Whd, WcatT);
  k_transT<<<NHH * NHH / 256, 256, 0, stream>>>(Wo, WoutT);
  k_cast<<<NHH * 1152 / 256, 256, 0, stream>>>(W1, W1h, NHH * 1152);
  k_s_hcat<<<NN * NS / 256, 256, 0, stream>>>(s, hcat);

  // layer 1: WhT1 = (x @ Wcat)^T ; per-head src/dst ; fused attention -> h1
  k_gemm<0><<<dim3(64, 8), 256, 0, stream>>>(xh, NFEAT, WcatT, NFEAT, (void*)WhT1, NN,
                                             (const float*)nullptr, NFEAT);
  k_srcdst<<<dim3(16, 8), 256, 0, stream>>>(WhT1, ah, sv1, dv1, NHID);
  k_attn<<<dim3(64, 8, JS), 256, 0, stream>>>(WhT1, sv1, dv1, NN, mb, pp, prs);
  k_combine<true><<<NN * NHH / 256, 256, 0, stream>>>(pp, prs, h1, NHH);

  // layer 2 (out_att): WhT2 = (h1 @ W_out)^T ; attention (no ELU) -> hcat[:, :512]
  k_gemm<0><<<dim3(64, 8), 256, 0, stream>>>(h1, NHH, WoutT, NHH, (void*)WhT2, NN,
                                             (const float*)nullptr, NHH);
  k_srcdst<<<dim3(16, 1), 256, 0, stream>>>(WhT2, ao, sv2, dv2, NHH);
  k_attn<<<dim3(64, 8, JS), 256, 0, stream>>>(WhT2, sv2, dv2, 0, mb, pp, prs);
  k_combine<false><<<NN * NHH / 256, 256, 0, stream>>>(pp, prs, hcat, 576);

  // edge MLP restructure: P = hcat@W1[:, :576]^T + b1 ; Q = hcat@W1[:, 576:]^T (f16 out)
  k_gemm<2><<<dim3(64, 8), 256, 0, stream>>>(hcat, 576, W1h, 1152, (void*)Pb, NHH, b1, 576);
  k_gemm<2><<<dim3(64, 8), 256, 0, stream>>>(hcat, 576, W1h + 576, 1152, (void*)Qb, NHH,
                                             (const float*)nullptr, 576);
  k_edge<<<NEDGE / 4, 256, 0, stream>>>(Pb, Qb, ids, W2, b2, out);
}

// Round 12
// 480.969 us; speedup vs baseline: 1.5215x; 1.5215x over previous
//
#include <hip/hip_runtime.h>

#define NN     4096
#define NFEAT  512
#define NHID   64
#define NHEADS 8
#define NS     64
#define NEDGE  131072
#define NHH    512
#define MASKW  (NN/32)   // 128 words per row
#define JS     4         // j-split factor for attention

typedef _Float16 f16;
typedef _Float16 f16x4 __attribute__((ext_vector_type(4)));
typedef _Float16 f16x8 __attribute__((ext_vector_type(8)));
typedef float    f32x4 __attribute__((ext_vector_type(4)));

// async global->LDS, 16B per lane, dest = wave-uniform base + lane*16
#define GLDS(gsrc, ldst) \
  __builtin_amdgcn_global_load_lds( \
      (const __attribute__((address_space(1))) void*)(gsrc), \
      (__attribute__((address_space(3))) void*)(ldst), 16, 0, 0)

// ---------------- prep kernels ----------------

__global__ __launch_bounds__(256) void k_pack_mask(const int* __restrict__ adj,
                                                   unsigned* __restrict__ mb) {
  int w = blockIdx.x * 256 + threadIdx.x;
  const int4* p = (const int4*)(adj + (size_t)w * 32);
  unsigned m = 0;
#pragma unroll
  for (int c = 0; c < 8; c++) {
    int4 v = p[c];
    m |= (v.x > 0 ? 1u : 0u) << (4*c)     | (v.y > 0 ? 1u : 0u) << (4*c + 1)
       | (v.z > 0 ? 1u : 0u) << (4*c + 2) | (v.w > 0 ? 1u : 0u) << (4*c + 3);
  }
  mb[w] = m;
}

__global__ __launch_bounds__(256) void k_cast(const float* __restrict__ in,
                                              f16* __restrict__ out, int n) {
  int i = blockIdx.x * 256 + threadIdx.x;
  if (i < n) out[i] = (f16)in[i];
}

// WcatT[n][k] = W_heads[n>>6][k][n&63]  (n = head*64+f), out [512][512] f16
__global__ __launch_bounds__(256) void k_wcatT(const float* __restrict__ W,
                                               f16* __restrict__ out) {
  int idx = blockIdx.x * 256 + threadIdx.x;
  int n = idx >> 9, k = idx & 511;
  out[idx] = (f16)W[(n >> 6) * (NFEAT * NHID) + k * NHID + (n & 63)];
}

// WoutT[n][k] = W_out[k][n]
__global__ __launch_bounds__(256) void k_transT(const float* __restrict__ W,
                                                f16* __restrict__ out) {
  int idx = blockIdx.x * 256 + threadIdx.x;
  int n = idx >> 9, k = idx & 511;
  out[idx] = (f16)W[k * NHH + n];
}

// hcat[i][512+c] = s[i][c]   (hcat leading dim 576)
__global__ __launch_bounds__(256) void k_s_hcat(const float* __restrict__ s,
                                                f16* __restrict__ hcat) {
  int idx = blockIdx.x * 256 + threadIdx.x;
  int i = idx >> 6, c = idx & 63;
  hcat[(size_t)i * 576 + 512 + c] = (f16)s[idx];
}

// ---------------- GEMM: C = A[M][lda] @ BT[n][k]^T ----------------
// LDS-staged B (the scattered operand): per 64-k chunk the block stages the
// 64-col x 64-k tile (8KB) coalesced via global_load_lds, double-buffered.
// XOR swizzle: slot p = c*8 + (o ^ (c&7)); writer is linear (lane*16), so the
// permutation is applied to the per-lane GLOBAL source (rule #21); reader
// applies the same XOR -> conflict-free ds_read_b128.
// MODE 0: C^T f16 to outT[n][ldo]; MODE 1: C f32 (+bias); MODE 2: C f16 (+bias)
template<int MODE>
__global__ __launch_bounds__(256) void k_gemm(const f16* __restrict__ A, int lda,
                                              const f16* __restrict__ BT, int ldbt,
                                              void* __restrict__ outp, int ldo,
                                              const float* __restrict__ bias, int K) {
  __shared__ __align__(16) char lds[2][8192];
  int tid = threadIdx.x;
  int w = tid >> 6, l = tid & 63, g = l >> 4, ln = l & 15;
  int row  = blockIdx.x * 64 + w * 16 + ln;
  int colb = blockIdx.y * 64;
  const f16* ap = A + (size_t)row * lda + 8 * g;
  // staging source: lane covers col colb + q*32 + w*8 + (l>>3), k-octet (l&7)^(l>>3)
  const int scol = w * 8 + (l >> 3);
  const int so8  = ((l & 7) ^ (l >> 3)) * 8;
  const f16* bs0 = BT + (size_t)(colb + scol) * ldbt + so8;
  const f16* bs1 = BT + (size_t)(colb + 32 + scol) * ldbt + so8;
  char* dst0 = &lds[0][0] + w * 1024;
  char* dst1 = &lds[0][0] + 4096 + w * 1024;
  f32x4 acc[4];
#pragma unroll
  for (int nf = 0; nf < 4; nf++) acc[nf] = (f32x4){0.f, 0.f, 0.f, 0.f};
  const int NCH = K >> 6;
  GLDS(bs0, dst0);
  GLDS(bs1, dst1);
  __syncthreads();
  for (int kc = 0; kc < NCH; ++kc) {
    const int buf = kc & 1;
    if (kc + 1 < NCH) {
      GLDS(bs0 + (kc + 1) * 64, dst0 + (buf ^ 1) * 8192);
      GLDS(bs1 + (kc + 1) * 64, dst1 + (buf ^ 1) * 8192);
    }
#pragma unroll
    for (int t2 = 0; t2 < 2; ++t2) {
      const int oo = t2 * 4 + g;
      const char* lb = &lds[buf][0];
      f16x8 c0 = *(const f16x8*)(lb + ((ln * 8)              + (oo ^ (ln & 7))) * 16);
      f16x8 c1 = *(const f16x8*)(lb + (((16 + ln) * 8)       + (oo ^ (ln & 7))) * 16);
      f16x8 c2 = *(const f16x8*)(lb + (((32 + ln) * 8)       + (oo ^ (ln & 7))) * 16);
      f16x8 c3 = *(const f16x8*)(lb + (((48 + ln) * 8)       + (oo ^ (ln & 7))) * 16);
      f16x8 af = *(const f16x8*)(ap + kc * 64 + t2 * 32);
      acc[0] = __builtin_amdgcn_mfma_f32_16x16x32_f16(af, c0, acc[0], 0, 0, 0);
      acc[1] = __builtin_amdgcn_mfma_f32_16x16x32_f16(af, c1, acc[1], 0, 0, 0);
      acc[2] = __builtin_amdgcn_mfma_f32_16x16x32_f16(af, c2, acc[2], 0, 0, 0);
      acc[3] = __builtin_amdgcn_mfma_f32_16x16x32_f16(af, c3, acc[3], 0, 0, 0);
    }
    __syncthreads();
  }
  int m0 = blockIdx.x * 64 + w * 16 + 4 * g;   // C/D: col=lane&15, row=4*(l>>4)+r (m89)
#pragma unroll
  for (int nf = 0; nf < 4; nf++) {
    int n = colb + nf * 16 + ln;
    if (MODE == 0) {
      f16* oT = (f16*)outp;
      f16x4 v = {(f16)acc[nf][0], (f16)acc[nf][1], (f16)acc[nf][2], (f16)acc[nf][3]};
      *(f16x4*)(oT + (size_t)n * ldo + m0) = v;
    } else if (MODE == 1) {
      float* o = (float*)outp;
      float b = bias ? bias[n] : 0.f;
#pragma unroll
      for (int r = 0; r < 4; r++) o[(size_t)(m0 + r) * ldo + n] = acc[nf][r] + b;
    } else {
      f16* o = (f16*)outp;
      float b = bias ? bias[n] : 0.f;
#pragma unroll
      for (int r = 0; r < 4; r++) o[(size_t)(m0 + r) * ldo + n] = (f16)(acc[nf][r] + b);
    }
  }
}

// src[h][i] = sum_f WhT[h*fo+f][i]*a[h][f];  dst uses a[h][fo+f]
__global__ __launch_bounds__(256) void k_srcdst(const f16* __restrict__ WhT,
                                                const float* __restrict__ a,
                                                float* __restrict__ sv,
                                                float* __restrict__ dv, int fo) {
  int h = blockIdx.y;
  int i = blockIdx.x * 256 + threadIdx.x;
  const f16* wp = WhT + (size_t)h * fo * NN + i;
  const float* ap = a + h * 2 * fo;
  float sacc = 0.f, dacc = 0.f;
  for (int f = 0; f < fo; f++) {
    float v = (float)wp[(size_t)f * NN];
    sacc = fmaf(v, ap[f], sacc);
    dacc = fmaf(v, ap[fo + f], dacc);
  }
  sv[h * NN + i] = sacc;
  dv[h * NN + i] = dacc;
}

// ---------------- fused masked GAT attention (flash-style, j-split) ----------------
// grid (64, 8, JS); block 64 rows x 64 cols, j-range 1024, j-chunk 64.
// B-tile (WhT slice) staged to LDS per chunk: coalesced global_load_lds,
// double-buffered, XOR-swizzled (same scheme as k_gemm) -> kills the
// 64-lines-per-load TA serialization that pinned r8/r10/r11 at ~160-170us.
__global__ __launch_bounds__(256, 8) void k_attn(const f16* __restrict__ WhT,
                                              const float* __restrict__ sv,
                                              const float* __restrict__ dv, int sstride,
                                              const unsigned* __restrict__ mb,
                                              float* __restrict__ pp,
                                              float* __restrict__ prs) {
  __shared__ __align__(16) char lds[2][8192];
  int tid = threadIdx.x;
  int w = tid >> 6, l = tid & 63, g = l >> 4, ln = l & 15;
  int i = blockIdx.x * 64 + w * 16 + ln;        // this lane's A-frag row
  int colbase = blockIdx.y * 64;
  int jz = blockIdx.z;
  const int jbase = jz * (NN / JS);
  const int NCH = (NN / JS) / 64;               // 16 chunks of 64 j
  float si = sv[blockIdx.y * sstride + i];
  const float* dpj = dv + blockIdx.y * sstride + jbase + 8 * g;
  const unsigned* mrow = mb + (size_t)i * MASKW + (jbase >> 5);
  // staging source: lane covers col colbase + q*32 + w*8 + (l>>3), j-octet (l&7)^(l>>3)
  const int scol = w * 8 + (l >> 3);
  const int so8  = ((l & 7) ^ (l >> 3)) * 8;
  const f16* bs0 = WhT + (size_t)(colbase + scol) * NN + jbase + so8;
  const f16* bs1 = WhT + (size_t)(colbase + 32 + scol) * NN + jbase + so8;
  char* dst0 = &lds[0][0] + w * 1024;
  char* dst1 = &lds[0][0] + 4096 + w * 1024;
  f32x4 acc[4];
#pragma unroll
  for (int nf = 0; nf < 4; nf++) acc[nf] = (f32x4){0.f, 0.f, 0.f, 0.f};
  float rsum = 0.f;
  GLDS(bs0, dst0);
  GLDS(bs1, dst1);
  __syncthreads();
  for (int ch = 0; ch < NCH; ++ch) {
    const int buf = ch & 1;
    if (ch + 1 < NCH) {                          // async prefetch next chunk
      GLDS(bs0 + (ch + 1) * 64, dst0 + (buf ^ 1) * 8192);
      GLDS(bs1 + (ch + 1) * 64, dst1 + (buf ^ 1) * 8192);
    }
#pragma unroll
    for (int t2 = 0; t2 < 2; ++t2) {
      unsigned mc = mrow[ch * 2 + t2];
      f32x4 dl = *(const f32x4*)(dpj + ch * 64 + t2 * 32);
      f32x4 dh = *(const f32x4*)(dpj + ch * 64 + t2 * 32 + 4);
      const int oo = t2 * 4 + g;
      const char* lb = &lds[buf][0];
      f16x8 c0 = *(const f16x8*)(lb + ((ln * 8)        + (oo ^ (ln & 7))) * 16);
      f16x8 c1 = *(const f16x8*)(lb + (((16 + ln) * 8) + (oo ^ (ln & 7))) * 16);
      f16x8 c2 = *(const f16x8*)(lb + (((32 + ln) * 8) + (oo ^ (ln & 7))) * 16);
      f16x8 c3 = *(const f16x8*)(lb + (((48 + ln) * 8) + (oo ^ (ln & 7))) * 16);
      f16x8 af;
#pragma unroll
      for (int d = 0; d < 4; d++) {
        float e = si + dl[d];
        e = fmaxf(e, 0.2f * e);                  // LeakyReLU(0.2)
        float we = __expf(e);
        we = ((mc >> (8 * g + d)) & 1u) ? we : 0.f;
        rsum += we;
        af[d] = (f16)we;
        float e2 = si + dh[d];
        e2 = fmaxf(e2, 0.2f * e2);
        float we2 = __expf(e2);
        we2 = ((mc >> (8 * g + 4 + d)) & 1u) ? we2 : 0.f;
        rsum += we2;
        af[4 + d] = (f16)we2;
      }
      acc[0] = __builtin_amdgcn_mfma_f32_16x16x32_f16(af, c0, acc[0], 0, 0, 0);
      acc[1] = __builtin_amdgcn_mfma_f32_16x16x32_f16(af, c1, acc[1], 0, 0, 0);
      acc[2] = __builtin_amdgcn_mfma_f32_16x16x32_f16(af, c2, acc[2], 0, 0, 0);
      acc[3] = __builtin_amdgcn_mfma_f32_16x16x32_f16(af, c3, acc[3], 0, 0, 0);
    }
    __syncthreads();
  }
  // full row sums over this j-range: 4 lanegroups hold disjoint partials of row (l&15)
  rsum += __shfl_xor(rsum, 16, 64);
  rsum += __shfl_xor(rsum, 32, 64);
  if (l < 16)
    prs[(size_t)jz * 8 * NN + blockIdx.y * NN + blockIdx.x * 64 + w * 16 + l] = rsum;
  float* o = pp + (size_t)jz * NN * NHH;
  int m0 = blockIdx.x * 64 + w * 16 + 4 * g;
#pragma unroll
  for (int nf = 0; nf < 4; nf++)
#pragma unroll
    for (int r = 0; r < 4; r++)
      o[(size_t)(m0 + r) * NHH + colbase + nf * 16 + ln] = acc[nf][r];
}

// combine j-split partials: out[i][c] = act( sum_jz pp / sum_jz prs )
template<bool ELU>
__global__ __launch_bounds__(256) void k_combine(const float* __restrict__ pp,
                                                 const float* __restrict__ prs,
                                                 f16* __restrict__ outp, int ldo) {
  int idx = blockIdx.x * 256 + threadIdx.x;       // over NN*NHH
  int i = idx >> 9, c = idx & 511;
  float s = 0.f, rs = 0.f;
#pragma unroll
  for (int jz = 0; jz < JS; jz++) {
    s  += pp[(size_t)jz * NN * NHH + idx];
    rs += prs[(size_t)jz * 8 * NN + (size_t)(c >> 6) * NN + i];
  }
  float v = s / rs;
  if (ELU) v = v > 0.f ? v : (__expf(v) - 1.f);
  outp[(size_t)i * ldo + c] = (f16)v;
}

// ---------------- edge MLP: out[e] = dot(relu(P[src]+Q[dst]), w2) + b2 ----------------
// P, Q in f16 (8 MB total -> L2/L3 resident)
__global__ __launch_bounds__(256) void k_edge(const f16* __restrict__ P,
                                              const f16* __restrict__ Q,
                                              const int* __restrict__ ids,
                                              const float* __restrict__ w2,
                                              const float* __restrict__ b2,
                                              float* __restrict__ out) {
  int t = blockIdx.x * 256 + threadIdx.x;
  int e = t >> 6, l = t & 63;                   // one wave per edge
  int sn = ids[2 * e], dn = ids[2 * e + 1];
  f16x8 pv = *(const f16x8*)(P + (size_t)sn * NHH + l * 8);
  f16x8 qv = *(const f16x8*)(Q + (size_t)dn * NHH + l * 8);
  const float* wv = w2 + l * 8;
  f32x4 w0 = *(const f32x4*)(wv);
  f32x4 w1 = *(const f32x4*)(wv + 4);
  float acc = 0.f;
#pragma unroll
  for (int u = 0; u < 4; u++) {
    float v = (float)pv[u] + (float)qv[u];
    acc = fmaf(fmaxf(v, 0.f), w0[u], acc);
    float v2 = (float)pv[4 + u] + (float)qv[4 + u];
    acc = fmaf(fmaxf(v2, 0.f), w1[u], acc);
  }
#pragma unroll
  for (int m = 1; m < 64; m <<= 1) acc += __shfl_xor(acc, m, 64);
  if (l == 0) out[e] = acc + b2[0];
}

// ---------------- launch ----------------
extern "C" void kernel_launch(void* const* d_in, const int* in_sizes, int n_in,
                              void* d_out, int out_size, void* d_ws, size_t ws_size,
                              hipStream_t stream) {
  const float* s   = (const float*)d_in[0];
  const float* x   = (const float*)d_in[1];
  const int*   adj = (const int*)d_in[2];
  const int*   ids = (const int*)d_in[3];
  const float* Whd = (const float*)d_in[4];
  const float* ah  = (const float*)d_in[5];
  const float* Wo  = (const float*)d_in[6];
  const float* ao  = (const float*)d_in[7];
  const float* W1  = (const float*)d_in[8];
  const float* b1  = (const float*)d_in[9];
  const float* W2  = (const float*)d_in[10];
  const float* b2  = (const float*)d_in[11];
  float* out = (float*)d_out;

  char* ws = (char*)d_ws;
  size_t off = 0;
  auto alloc = [&](size_t b) { char* p = ws + off; off += (b + 255) & ~(size_t)255; return p; };
  unsigned* mb  = (unsigned*)alloc((size_t)NN * MASKW * 4);   // 2 MB
  f16* xh       = (f16*)alloc((size_t)NN * NFEAT * 2);        // 4 MB
  f16* WcatT    = (f16*)alloc((size_t)NHH * NFEAT * 2);
  f16* WoutT    = (f16*)alloc((size_t)NHH * NHH * 2);
  f16* W1h      = (f16*)alloc((size_t)NHH * 1152 * 2);
  f16* WhT1     = (f16*)alloc((size_t)NHH * NN * 2);          // 4 MB
  f16* h1       = (f16*)alloc((size_t)NN * NHH * 2);          // 4 MB
  f16* WhT2     = (f16*)alloc((size_t)NHH * NN * 2);          // 4 MB
  f16* hcat     = (f16*)alloc((size_t)NN * 576 * 2);          // 4.5 MB
  float* sv1    = (float*)alloc((size_t)NHEADS * NN * 4);
  float* dv1    = (float*)alloc((size_t)NHEADS * NN * 4);
  float* sv2    = (float*)alloc((size_t)NN * 4);
  float* dv2    = (float*)alloc((size_t)NN * 4);
  // union region: attn partials (32.5 MB) then, after combine, Pb/Qb (f16, 4 MB each)
  char* region  = alloc((size_t)JS * NN * NHH * 4 + (size_t)JS * 8 * NN * 4);
  float* pp     = (float*)region;
  float* prs    = (float*)(region + (size_t)JS * NN * NHH * 4);
  f16* Pb       = (f16*)region;
  f16* Qb       = (f16*)(region + (size_t)NN * NHH * 2);

  k_pack_mask<<<NN * MASKW / 256, 256, 0, stream>>>(adj, mb);
  k_cast<<<NN * NFEAT / 256, 256, 0, stream>>>(x, xh, NN * NFEAT);
  k_wcatT<<<NHH * NFEAT / 256, 256, 0, stream>>>(Whd, WcatT);
  k_transT<<<NHH * NHH / 256, 256, 0, stream>>>(Wo, WoutT);
  k_cast<<<NHH * 1152 / 256, 256, 0, stream>>>(W1, W1h, NHH * 1152);
  k_s_hcat<<<NN * NS / 256, 256, 0, stream>>>(s, hcat);

  // layer 1: WhT1 = (x @ Wcat)^T ; per-head src/dst ; fused attention -> h1
  k_gemm<0><<<dim3(64, 8), 256, 0, stream>>>(xh, NFEAT, WcatT, NFEAT, (void*)WhT1, NN,
                                             (const float*)nullptr, NFEAT);
  k_srcdst<<<dim3(16, 8), 256, 0, stream>>>(WhT1, ah, sv1, dv1, NHID);
  k_attn<<<dim3(64, 8, JS), 256, 0, stream>>>(WhT1, sv1, dv1, NN, mb, pp, prs);
  k_combine<true><<<NN * NHH / 256, 256, 0, stream>>>(pp, prs, h1, NHH);

  // layer 2 (out_att): WhT2 = (h1 @ W_out)^T ; attention (no ELU) -> hcat[:, :512]
  k_gemm<0><<<dim3(64, 8), 256, 0, stream>>>(h1, NHH, WoutT, NHH, (void*)WhT2, NN,
                                             (const float*)nullptr, NHH);
  k_srcdst<<<dim3(16, 1), 256, 0, stream>>>(WhT2, ao, sv2, dv2, NHH);
  k_attn<<<dim3(64, 8, JS), 256, 0, stream>>>(WhT2, sv2, dv2, 0, mb, pp, prs);
  k_combine<false><<<NN * NHH / 256, 256, 0, stream>>>(pp, prs, hcat, 576);

  // edge MLP restructure: P = hcat@W1[:, :576]^T + b1 ; Q = hcat@W1[:, 576:]^T (f16 out)
  k_gemm<2><<<dim3(64, 8), 256, 0, stream>>>(hcat, 576, W1h, 1152, (void*)Pb, NHH, b1, 576);
  k_gemm<2><<<dim3(64, 8), 256, 0, stream>>>(hcat, 576, W1h + 576, 1152, (void*)Qb, NHH,
                                             (const float*)nullptr, 576);
  k_edge<<<NEDGE / 4, 256, 0, stream>>>(Pb, Qb, ids, W2, b2, out);
}

// Round 13
// 366.644 us; speedup vs baseline: 1.9959x; 1.3118x over previous
//
#include <hip/hip_runtime.h>

#define NN     4096
#define NFEAT  512
#define NHID   64
#define NHEADS 8
#define NS     64
#define NEDGE  131072
#define NHH    512
#define MASKW  (NN/32)   // 128 words per row
#define JS     4         // j-split factor for attention

typedef _Float16 f16;
typedef _Float16 f16x4 __attribute__((ext_vector_type(4)));
typedef _Float16 f16x8 __attribute__((ext_vector_type(8)));
typedef float    f32x4 __attribute__((ext_vector_type(4)));

// async global->LDS, 16B per lane, dest = wave-uniform base + lane*16
#define GLDS(gsrc, ldst) \
  __builtin_amdgcn_global_load_lds( \
      (const __attribute__((address_space(1))) void*)(gsrc), \
      (__attribute__((address_space(3))) void*)(ldst), 16, 0, 0)

// ---------------- prep kernels ----------------

__global__ __launch_bounds__(256) void k_pack_mask(const int* __restrict__ adj,
                                                   unsigned* __restrict__ mb) {
  int w = blockIdx.x * 256 + threadIdx.x;
  const int4* p = (const int4*)(adj + (size_t)w * 32);
  unsigned m = 0;
#pragma unroll
  for (int c = 0; c < 8; c++) {
    int4 v = p[c];
    m |= (v.x > 0 ? 1u : 0u) << (4*c)     | (v.y > 0 ? 1u : 0u) << (4*c + 1)
       | (v.z > 0 ? 1u : 0u) << (4*c + 2) | (v.w > 0 ? 1u : 0u) << (4*c + 3);
  }
  mb[w] = m;
}

__global__ __launch_bounds__(256) void k_cast(const float* __restrict__ in,
                                              f16* __restrict__ out, int n) {
  int i = blockIdx.x * 256 + threadIdx.x;
  if (i < n) out[i] = (f16)in[i];
}

// WcatT[n][k] = W_heads[n>>6][k][n&63]  (n = head*64+f), out [512][512] f16
__global__ __launch_bounds__(256) void k_wcatT(const float* __restrict__ W,
                                               f16* __restrict__ out) {
  int idx = blockIdx.x * 256 + threadIdx.x;
  int n = idx >> 9, k = idx & 511;
  out[idx] = (f16)W[(n >> 6) * (NFEAT * NHID) + k * NHID + (n & 63)];
}

// WoutT[n][k] = W_out[k][n]
__global__ __launch_bounds__(256) void k_transT(const float* __restrict__ W,
                                                f16* __restrict__ out) {
  int idx = blockIdx.x * 256 + threadIdx.x;
  int n = idx >> 9, k = idx & 511;
  out[idx] = (f16)W[k * NHH + n];
}

// hcat[i][512+c] = s[i][c]   (hcat leading dim 576)
__global__ __launch_bounds__(256) void k_s_hcat(const float* __restrict__ s,
                                                f16* __restrict__ hcat) {
  int idx = blockIdx.x * 256 + threadIdx.x;
  int i = idx >> 6, c = idx & 63;
  hcat[(size_t)i * 576 + 512 + c] = (f16)s[idx];
}

// ---------------- GEMM: C = A[M][lda] @ BT[n][k]^T ----------------
// LDS-staged B, double-buffered, XOR-swizzled (r12-verified).
// MODE 0: C^T f16 to outT[n][ldo]; MODE 1: C f32 (+bias); MODE 2: C f16 (+bias)
template<int MODE>
__global__ __launch_bounds__(256) void k_gemm(const f16* __restrict__ A, int lda,
                                              const f16* __restrict__ BT, int ldbt,
                                              void* __restrict__ outp, int ldo,
                                              const float* __restrict__ bias, int K) {
  __shared__ __align__(16) char lds[2][8192];
  int tid = threadIdx.x;
  int w = tid >> 6, l = tid & 63, g = l >> 4, ln = l & 15;
  int row  = blockIdx.x * 64 + w * 16 + ln;
  int colb = blockIdx.y * 64;
  const f16* ap = A + (size_t)row * lda + 8 * g;
  const int scol = w * 8 + (l >> 3);
  const int so8  = ((l & 7) ^ (l >> 3)) * 8;
  const f16* bs0 = BT + (size_t)(colb + scol) * ldbt + so8;
  const f16* bs1 = BT + (size_t)(colb + 32 + scol) * ldbt + so8;
  char* dst0 = &lds[0][0] + w * 1024;
  char* dst1 = &lds[0][0] + 4096 + w * 1024;
  f32x4 acc[4];
#pragma unroll
  for (int nf = 0; nf < 4; nf++) acc[nf] = (f32x4){0.f, 0.f, 0.f, 0.f};
  const int NCH = K >> 6;
  GLDS(bs0, dst0);
  GLDS(bs1, dst1);
  __syncthreads();
  for (int kc = 0; kc < NCH; ++kc) {
    const int buf = kc & 1;
    if (kc + 1 < NCH) {
      GLDS(bs0 + (kc + 1) * 64, dst0 + (buf ^ 1) * 8192);
      GLDS(bs1 + (kc + 1) * 64, dst1 + (buf ^ 1) * 8192);
    }
#pragma unroll
    for (int t2 = 0; t2 < 2; ++t2) {
      const int oo = t2 * 4 + g;
      const char* lb = &lds[buf][0];
      f16x8 c0 = *(const f16x8*)(lb + ((ln * 8)              + (oo ^ (ln & 7))) * 16);
      f16x8 c1 = *(const f16x8*)(lb + (((16 + ln) * 8)       + (oo ^ (ln & 7))) * 16);
      f16x8 c2 = *(const f16x8*)(lb + (((32 + ln) * 8)       + (oo ^ (ln & 7))) * 16);
      f16x8 c3 = *(const f16x8*)(lb + (((48 + ln) * 8)       + (oo ^ (ln & 7))) * 16);
      f16x8 af = *(const f16x8*)(ap + kc * 64 + t2 * 32);
      acc[0] = __builtin_amdgcn_mfma_f32_16x16x32_f16(af, c0, acc[0], 0, 0, 0);
      acc[1] = __builtin_amdgcn_mfma_f32_16x16x32_f16(af, c1, acc[1], 0, 0, 0);
      acc[2] = __builtin_amdgcn_mfma_f32_16x16x32_f16(af, c2, acc[2], 0, 0, 0);
      acc[3] = __builtin_amdgcn_mfma_f32_16x16x32_f16(af, c3, acc[3], 0, 0, 0);
    }
    __syncthreads();
  }
  int m0 = blockIdx.x * 64 + w * 16 + 4 * g;   // C/D: col=lane&15, row=4*(l>>4)+r (m89)
#pragma unroll
  for (int nf = 0; nf < 4; nf++) {
    int n = colb + nf * 16 + ln;
    if (MODE == 0) {
      f16* oT = (f16*)outp;
      f16x4 v = {(f16)acc[nf][0], (f16)acc[nf][1], (f16)acc[nf][2], (f16)acc[nf][3]};
      *(f16x4*)(oT + (size_t)n * ldo + m0) = v;
    } else if (MODE == 1) {
      float* o = (float*)outp;
      float b = bias ? bias[n] : 0.f;
#pragma unroll
      for (int r = 0; r < 4; r++) o[(size_t)(m0 + r) * ldo + n] = acc[nf][r] + b;
    } else {
      f16* o = (f16*)outp;
      float b = bias ? bias[n] : 0.f;
#pragma unroll
      for (int r = 0; r < 4; r++) o[(size_t)(m0 + r) * ldo + n] = (f16)(acc[nf][r] + b);
    }
  }
}

// ---------------- src/dst score vectors, f-split (r12: 0.7% occupancy fix) ----
// partial: svp[(fz*H + h)*NN + i] = sum_{f in chunk} WhT[h*fo+f][i] * a[h][f]
__global__ __launch_bounds__(256) void k_srcdst_p(const f16* __restrict__ WhT,
                                                  const float* __restrict__ a,
                                                  float* __restrict__ svp,
                                                  float* __restrict__ dvp,
                                                  int fo, int chunk) {
  int h = blockIdx.y, fz = blockIdx.z, H = gridDim.y;
  int i = blockIdx.x * 256 + threadIdx.x;
  int f0 = fz * chunk;
  const f16* wp = WhT + ((size_t)h * fo + f0) * NN + i;
  const float* ap = a + h * 2 * fo + f0;
  float sacc = 0.f, dacc = 0.f;
  for (int f = 0; f < chunk; f++) {
    float v = (float)wp[(size_t)f * NN];
    sacc = fmaf(v, ap[f], sacc);
    dacc = fmaf(v, ap[fo + f], dacc);
  }
  svp[((size_t)fz * H + h) * NN + i] = sacc;
  dvp[((size_t)fz * H + h) * NN + i] = dacc;
}

// reduce over fz: sv[idx] = sum_fz svp[fz*HNN + idx]
__global__ __launch_bounds__(256) void k_srcdst_r(const float* __restrict__ svp,
                                                  const float* __restrict__ dvp,
                                                  float* __restrict__ sv,
                                                  float* __restrict__ dv,
                                                  int HNN, int FZ) {
  int idx = blockIdx.x * 256 + threadIdx.x;
  float s = 0.f, d = 0.f;
  for (int fz = 0; fz < FZ; fz++) {
    s += svp[(size_t)fz * HNN + idx];
    d += dvp[(size_t)fz * HNN + idx];
  }
  sv[idx] = s;
  dv[idx] = d;
}

// ---------------- fused masked GAT attention (flash-style, j-split) ----------------
// Flat grid 2048 with bijective XCD swizzle (2048%8==0): each XCD gets 4
// contiguous (by,jz) groups -> 512KB L2 footprint (r12 FETCH 24.6MB showed
// cross-XCD duplication). LDS-staged B, double-buffered, XOR-swizzled (r12).
__global__ __launch_bounds__(256, 8) void k_attn(const f16* __restrict__ WhT,
                                              const float* __restrict__ sv,
                                              const float* __restrict__ dv, int sstride,
                                              const unsigned* __restrict__ mb,
                                              float* __restrict__ pp,
                                              float* __restrict__ prs) {
  __shared__ __align__(16) char lds[2][8192];
  int wgid = blockIdx.x;
  int swz = ((wgid & 7) << 8) + (wgid >> 3);    // XCD-contiguous remap
  int bx = swz & 63, by = (swz >> 6) & 7, jz = swz >> 9;
  int tid = threadIdx.x;
  int w = tid >> 6, l = tid & 63, g = l >> 4, ln = l & 15;
  int i = bx * 64 + w * 16 + ln;                // this lane's A-frag row
  int colbase = by * 64;
  const int jbase = jz * (NN / JS);
  const int NCH = (NN / JS) / 64;               // 16 chunks of 64 j
  float si = sv[by * sstride + i];
  const float* dpj = dv + by * sstride + jbase + 8 * g;
  const unsigned* mrow = mb + (size_t)i * MASKW + (jbase >> 5);
  const int scol = w * 8 + (l >> 3);
  const int so8  = ((l & 7) ^ (l >> 3)) * 8;
  const f16* bs0 = WhT + (size_t)(colbase + scol) * NN + jbase + so8;
  const f16* bs1 = WhT + (size_t)(colbase + 32 + scol) * NN + jbase + so8;
  char* dst0 = &lds[0][0] + w * 1024;
  char* dst1 = &lds[0][0] + 4096 + w * 1024;
  f32x4 acc[4];
#pragma unroll
  for (int nf = 0; nf < 4; nf++) acc[nf] = (f32x4){0.f, 0.f, 0.f, 0.f};
  float rsum = 0.f;
  GLDS(bs0, dst0);
  GLDS(bs1, dst1);
  __syncthreads();
  for (int ch = 0; ch < NCH; ++ch) {
    const int buf = ch & 1;
    if (ch + 1 < NCH) {                          // async prefetch next chunk
      GLDS(bs0 + (ch + 1) * 64, dst0 + (buf ^ 1) * 8192);
      GLDS(bs1 + (ch + 1) * 64, dst1 + (buf ^ 1) * 8192);
    }
#pragma unroll
    for (int t2 = 0; t2 < 2; ++t2) {
      unsigned mc = mrow[ch * 2 + t2];
      f32x4 dl = *(const f32x4*)(dpj + ch * 64 + t2 * 32);
      f32x4 dh = *(const f32x4*)(dpj + ch * 64 + t2 * 32 + 4);
      const int oo = t2 * 4 + g;
      const char* lb = &lds[buf][0];
      f16x8 c0 = *(const f16x8*)(lb + ((ln * 8)        + (oo ^ (ln & 7))) * 16);
      f16x8 c1 = *(const f16x8*)(lb + (((16 + ln) * 8) + (oo ^ (ln & 7))) * 16);
      f16x8 c2 = *(const f16x8*)(lb + (((32 + ln) * 8) + (oo ^ (ln & 7))) * 16);
      f16x8 c3 = *(const f16x8*)(lb + (((48 + ln) * 8) + (oo ^ (ln & 7))) * 16);
      f16x8 af;
#pragma unroll
      for (int d = 0; d < 4; d++) {
        float e = si + dl[d];
        e = fmaxf(e, 0.2f * e);                  // LeakyReLU(0.2)
        float we = __expf(e);
        we = ((mc >> (8 * g + d)) & 1u) ? we : 0.f;
        rsum += we;
        af[d] = (f16)we;
        float e2 = si + dh[d];
        e2 = fmaxf(e2, 0.2f * e2);
        float we2 = __expf(e2);
        we2 = ((mc >> (8 * g + 4 + d)) & 1u) ? we2 : 0.f;
        rsum += we2;
        af[4 + d] = (f16)we2;
      }
      acc[0] = __builtin_amdgcn_mfma_f32_16x16x32_f16(af, c0, acc[0], 0, 0, 0);
      acc[1] = __builtin_amdgcn_mfma_f32_16x16x32_f16(af, c1, acc[1], 0, 0, 0);
      acc[2] = __builtin_amdgcn_mfma_f32_16x16x32_f16(af, c2, acc[2], 0, 0, 0);
      acc[3] = __builtin_amdgcn_mfma_f32_16x16x32_f16(af, c3, acc[3], 0, 0, 0);
    }
    __syncthreads();
  }
  // full row sums over this j-range: 4 lanegroups hold disjoint partials of row (l&15)
  rsum += __shfl_xor(rsum, 16, 64);
  rsum += __shfl_xor(rsum, 32, 64);
  if (l < 16)
    prs[(size_t)jz * 8 * NN + by * NN + bx * 64 + w * 16 + l] = rsum;
  float* o = pp + (size_t)jz * NN * NHH;
  int m0 = bx * 64 + w * 16 + 4 * g;
#pragma unroll
  for (int nf = 0; nf < 4; nf++)
#pragma unroll
    for (int r = 0; r < 4; r++)
      o[(size_t)(m0 + r) * NHH + colbase + nf * 16 + ln] = acc[nf][r];
}

// combine j-split partials: out[i][c] = act( sum_jz pp / sum_jz prs )
template<bool ELU>
__global__ __launch_bounds__(256) void k_combine(const float* __restrict__ pp,
                                                 const float* __restrict__ prs,
                                                 f16* __restrict__ outp, int ldo) {
  int idx = blockIdx.x * 256 + threadIdx.x;       // over NN*NHH
  int i = idx >> 9, c = idx & 511;
  float s = 0.f, rs = 0.f;
#pragma unroll
  for (int jz = 0; jz < JS; jz++) {
    s  += pp[(size_t)jz * NN * NHH + idx];
    rs += prs[(size_t)jz * 8 * NN + (size_t)(c >> 6) * NN + i];
  }
  float v = s / rs;
  if (ELU) v = v > 0.f ? v : (__expf(v) - 1.f);
  outp[(size_t)i * ldo + c] = (f16)v;
}

// ---------------- edge MLP: out[e] = dot(relu(P[src]+Q[dst]), w2) + b2 ----------------
__global__ __launch_bounds__(256) void k_edge(const f16* __restrict__ P,
                                              const f16* __restrict__ Q,
                                              const int* __restrict__ ids,
                                              const float* __restrict__ w2,
                                              const float* __restrict__ b2,
                                              float* __restrict__ out) {
  int t = blockIdx.x * 256 + threadIdx.x;
  int e = t >> 6, l = t & 63;                   // one wave per edge
  int sn = ids[2 * e], dn = ids[2 * e + 1];
  f16x8 pv = *(const f16x8*)(P + (size_t)sn * NHH + l * 8);
  f16x8 qv = *(const f16x8*)(Q + (size_t)dn * NHH + l * 8);
  const float* wv = w2 + l * 8;
  f32x4 w0 = *(const f32x4*)(wv);
  f32x4 w1 = *(const f32x4*)(wv + 4);
  float acc = 0.f;
#pragma unroll
  for (int u = 0; u < 4; u++) {
    float v = (float)pv[u] + (float)qv[u];
    acc = fmaf(fmaxf(v, 0.f), w0[u], acc);
    float v2 = (float)pv[4 + u] + (float)qv[4 + u];
    acc = fmaf(fmaxf(v2, 0.f), w1[u], acc);
  }
#pragma unroll
  for (int m = 1; m < 64; m <<= 1) acc += __shfl_xor(acc, m, 64);
  if (l == 0) out[e] = acc + b2[0];
}

// ---------------- launch ----------------
extern "C" void kernel_launch(void* const* d_in, const int* in_sizes, int n_in,
                              void* d_out, int out_size, void* d_ws, size_t ws_size,
                              hipStream_t stream) {
  const float* s   = (const float*)d_in[0];
  const float* x   = (const float*)d_in[1];
  const int*   adj = (const int*)d_in[2];
  const int*   ids = (const int*)d_in[3];
  const float* Whd = (const float*)d_in[4];
  const float* ah  = (const float*)d_in[5];
  const float* Wo  = (const float*)d_in[6];
  const float* ao  = (const float*)d_in[7];
  const float* W1  = (const float*)d_in[8];
  const float* b1  = (const float*)d_in[9];
  const float* W2  = (const float*)d_in[10];
  const float* b2  = (const float*)d_in[11];
  float* out = (float*)d_out;

  char* ws = (char*)d_ws;
  size_t off = 0;
  auto alloc = [&](size_t b) { char* p = ws + off; off += (b + 255) & ~(size_t)255; return p; };
  unsigned* mb  = (unsigned*)alloc((size_t)NN * MASKW * 4);   // 2 MB
  f16* xh       = (f16*)alloc((size_t)NN * NFEAT * 2);        // 4 MB
  f16* WcatT    = (f16*)alloc((size_t)NHH * NFEAT * 2);
  f16* WoutT    = (f16*)alloc((size_t)NHH * NHH * 2);
  f16* W1h      = (f16*)alloc((size_t)NHH * 1152 * 2);
  f16* WhT1     = (f16*)alloc((size_t)NHH * NN * 2);          // 4 MB
  f16* h1       = (f16*)alloc((size_t)NN * NHH * 2);          // 4 MB
  f16* WhT2     = (f16*)alloc((size_t)NHH * NN * 2);          // 4 MB
  f16* hcat     = (f16*)alloc((size_t)NN * 576 * 2);          // 4.5 MB
  float* sv1    = (float*)alloc((size_t)NHEADS * NN * 4);
  float* dv1    = (float*)alloc((size_t)NHEADS * NN * 4);
  float* sv2    = (float*)alloc((size_t)NN * 4);
  float* dv2    = (float*)alloc((size_t)NN * 4);
  float* svp    = (float*)alloc((size_t)64 * NN * 4);         // 1 MB (f-split partials)
  float* dvp    = (float*)alloc((size_t)64 * NN * 4);         // 1 MB
  // union region: attn partials (32.5 MB) then, after combine, Pb/Qb (f16, 4 MB each)
  char* region  = alloc((size_t)JS * NN * NHH * 4 + (size_t)JS * 8 * NN * 4);
  float* pp     = (float*)region;
  float* prs    = (float*)(region + (size_t)JS * NN * NHH * 4);
  f16* Pb       = (f16*)region;
  f16* Qb       = (f16*)(region + (size_t)NN * NHH * 2);

  k_pack_mask<<<NN * MASKW / 256, 256, 0, stream>>>(adj, mb);
  k_cast<<<NN * NFEAT / 256, 256, 0, stream>>>(x, xh, NN * NFEAT);
  k_wcatT<<<NHH * NFEAT / 256, 256, 0, stream>>>(Whd, WcatT);
  k_transT<<<NHH * NHH / 256, 256, 0, stream>>>(Wo, WoutT);
  k_cast<<<NHH * 1152 / 256, 256, 0, stream>>>(W1, W1h, NHH * 1152);
  k_s_hcat<<<NN * NS / 256, 256, 0, stream>>>(s, hcat);

  // layer 1: WhT1 = (x @ Wcat)^T ; per-head src/dst (f-split) ; attention -> h1
  k_gemm<0><<<dim3(64, 8), 256, 0, stream>>>(xh, NFEAT, WcatT, NFEAT, (void*)WhT1, NN,
                                             (const float*)nullptr, NFEAT);
  k_srcdst_p<<<dim3(16, 8, 8), 256, 0, stream>>>(WhT1, ah, svp, dvp, NHID, 8);
  k_srcdst_r<<<NHEADS * NN / 256, 256, 0, stream>>>(svp, dvp, sv1, dv1, NHEADS * NN, 8);
  k_attn<<<2048, 256, 0, stream>>>(WhT1, sv1, dv1, NN, mb, pp, prs);
  k_combine<true><<<NN * NHH / 256, 256, 0, stream>>>(pp, prs, h1, NHH);

  // layer 2 (out_att): WhT2 = (h1 @ W_out)^T ; src/dst (f-split) ; attention -> hcat
  k_gemm<0><<<dim3(64, 8), 256, 0, stream>>>(h1, NHH, WoutT, NHH, (void*)WhT2, NN,
                                             (const float*)nullptr, NHH);
  k_srcdst_p<<<dim3(16, 1, 32), 256, 0, stream>>>(WhT2, ao, svp, dvp, NHH, 16);
  k_srcdst_r<<<NN / 256, 256, 0, stream>>>(svp, dvp, sv2, dv2, NN, 32);
  k_attn<<<2048, 256, 0, stream>>>(WhT2, sv2, dv2, 0, mb, pp, prs);
  k_combine<false><<<NN * NHH / 256, 256, 0, stream>>>(pp, prs, hcat, 576);

  // edge MLP restructure: P = hcat@W1[:, :576]^T + b1 ; Q = hcat@W1[:, 576:]^T (f16 out)
  k_gemm<2><<<dim3(64, 8), 256, 0, stream>>>(hcat, 576, W1h, 1152, (void*)Pb, NHH, b1, 576);
  k_gemm<2><<<dim3(64, 8), 256, 0, stream>>>(hcat, 576, W1h + 576, 1152, (void*)Qb, NHH,
                                             (const float*)nullptr, 576);
  k_edge<<<NEDGE / 4, 256, 0, stream>>>(Pb, Qb, ids, W2, b2, out);
}